// Round 3
// baseline (195.018 us; speedup 1.0000x reference)
//
#include <hip/hip_runtime.h>
#include <hip/hip_bf16.h>

#define EPS 1e-5f

// ---- workspace layout (float offsets) ----
#define OFF_ABAR 0          // 128*64*72   = 589824   floats
#define OFF_U    589824     // 128*64*256  = 2097152
#define OFF_V    2686976    // 2097152
#define OFF_PART 4784128    // 128*16*256  = 524288  -> total 5308416 fl = 21.2 MB

// K1: fused split-embedding + LayerNorm over (N,E) per batch.
// block = 256 threads, one block per batch b. Each thread owns 18 of the 4608
// elements (k = tid + 256*m). Boundary n==32 falls at m==9 -> wave-uniform.
__global__ __launch_bounds__(256) void k_embed_ln0(
    const float* __restrict__ xa, const float* __restrict__ xb,
    const float* __restrict__ Wa, const float* __restrict__ ba,
    const float* __restrict__ Wb, const float* __restrict__ bb,
    const float* __restrict__ g0, const float* __restrict__ b0,
    float* __restrict__ abar) {
    int b = blockIdx.x;
    int tid = threadIdx.x;
    float vals[18];
    float s1 = 0.f, s2 = 0.f;
    for (int m = 0; m < 18; ++m) {
        int k = tid + 256 * m;
        int e = k % 72;
        int n = k / 72;
        float acc;
        if (n < 32) {
            acc = ba[e];
            const float* x = xa + (b * 32 + n) * 23;
            #pragma unroll
            for (int d = 0; d < 23; ++d) acc = fmaf(x[d], Wa[d * 72 + e], acc);
        } else {
            acc = bb[e];
            const float* x = xb + (b * 32 + (n - 32)) * 13;
            #pragma unroll
            for (int d = 0; d < 13; ++d) acc = fmaf(x[d], Wb[d * 72 + e], acc);
        }
        vals[m] = acc;
        s1 += acc;
        s2 = fmaf(acc, acc, s2);
    }
    #pragma unroll
    for (int off = 32; off >= 1; off >>= 1) {
        s1 += __shfl_xor(s1, off, 64);
        s2 += __shfl_xor(s2, off, 64);
    }
    __shared__ float r1[4], r2[4];
    int w = tid >> 6;
    if ((tid & 63) == 0) { r1[w] = s1; r2[w] = s2; }
    __syncthreads();
    float t1 = r1[0] + r1[1] + r1[2] + r1[3];
    float t2 = r2[0] + r2[1] + r2[2] + r2[3];
    float mean = t1 * (1.f / 4608.f);
    float var  = fmaf(-mean, mean, t2 * (1.f / 4608.f));
    float rsq  = rsqrtf(var + EPS);
    float* ab = abar + b * 4608;
    for (int m = 0; m < 18; ++m) {
        int k = tid + 256 * m;
        ab[k] = fmaf((vals[m] - mean) * rsq, g0[k], b0[k]);
    }
}

// K2: U = abar @ Wg[0:72,:] (+ b_g folded in), V = abar @ Wg[72:144,:].
// grid = 128 b * 4 n-quarters, block = 256 (thread = one h column).
__global__ __launch_bounds__(256) void k_uv(
    const float* __restrict__ abar, const float* __restrict__ Wg,
    const float* __restrict__ bg,
    float* __restrict__ U, float* __restrict__ V) {
    int blk = blockIdx.x;            // 512 blocks
    int b = blk >> 2;
    int q = blk & 3;                 // n-range [q*16, q*16+16)
    int h = threadIdx.x;
    __shared__ float sa[72 * 16];    // [e][n], 4.5 KB
    const float* src = abar + (b * 64 + q * 16) * 72;
    for (int k = threadIdx.x; k < 72 * 16; k += 256) {
        int e = k >> 4, n = k & 15;
        sa[k] = src[n * 72 + e];
    }
    __syncthreads();
    float u[16], v[16];
    #pragma unroll
    for (int n = 0; n < 16; ++n) { u[n] = 0.f; v[n] = 0.f; }
    for (int e = 0; e < 72; ++e) {
        float wu = Wg[e * 256 + h];
        float wv = Wg[(72 + e) * 256 + h];
        const float4* sp = (const float4*)&sa[e * 16];
        #pragma unroll
        for (int n4 = 0; n4 < 4; ++n4) {
            float4 s4 = sp[n4];
            u[n4*4+0] = fmaf(s4.x, wu, u[n4*4+0]); v[n4*4+0] = fmaf(s4.x, wv, v[n4*4+0]);
            u[n4*4+1] = fmaf(s4.y, wu, u[n4*4+1]); v[n4*4+1] = fmaf(s4.y, wv, v[n4*4+1]);
            u[n4*4+2] = fmaf(s4.z, wu, u[n4*4+2]); v[n4*4+2] = fmaf(s4.z, wv, v[n4*4+2]);
            u[n4*4+3] = fmaf(s4.w, wu, u[n4*4+3]); v[n4*4+3] = fmaf(s4.w, wv, v[n4*4+3]);
        }
    }
    float bgh = bg[h];
    int base = (b * 64 + q * 16) * 256 + h;
    #pragma unroll
    for (int n = 0; n < 16; ++n) {
        U[base + n * 256] = u[n] + bgh;   // b_g folded into U
        V[base + n * 256] = v[n];
    }
}

// K3: pairwise elu + LayerNorm(256) + sum over pairs.
// grid = 128 b * 16 i-chunks; block = 4 waves, wave w owns i = p*4+w, all 64 j.
// lane l owns h = 4l..4l+3. V[b] staged in LDS in two 32-row chunks (32 KB).
__global__ __launch_bounds__(256) void k_pair(
    const float* __restrict__ U, const float* __restrict__ V,
    float* __restrict__ part) {
    int b = blockIdx.x >> 4;
    int p = blockIdx.x & 15;
    int tid = threadIdx.x;
    int w = tid >> 6, l = tid & 63;
    int i = p * 4 + w;
    __shared__ float Vs[32 * 256];   // 32 KB
    const float* Vb = V + b * 16384;
    float4 u4 = *(const float4*)&U[(b * 64 + i) * 256 + l * 4];
    float4 acc = make_float4(0.f, 0.f, 0.f, 0.f);
    for (int c = 0; c < 2; ++c) {
        __syncthreads();
        for (int k = tid * 4; k < 8192; k += 1024)
            *(float4*)&Vs[k] = *(const float4*)&Vb[c * 8192 + k];
        __syncthreads();
        for (int j = 0; j < 32; ++j) {
            float4 v4 = *(const float4*)&Vs[j * 256 + l * 4];
            float z0 = u4.x + v4.x, z1 = u4.y + v4.y;
            float z2 = u4.z + v4.z, z3 = u4.w + v4.w;
            float e0 = z0 > 0.f ? z0 : __expf(z0) - 1.f;
            float e1 = z1 > 0.f ? z1 : __expf(z1) - 1.f;
            float e2 = z2 > 0.f ? z2 : __expf(z2) - 1.f;
            float e3 = z3 > 0.f ? z3 : __expf(z3) - 1.f;
            float s1 = (e0 + e1) + (e2 + e3);
            float s2 = fmaf(e0, e0, fmaf(e1, e1, fmaf(e2, e2, e3 * e3)));
            #pragma unroll
            for (int off = 32; off >= 1; off >>= 1) {
                s1 += __shfl_xor(s1, off, 64);
                s2 += __shfl_xor(s2, off, 64);
            }
            float mu  = s1 * (1.f / 256.f);
            float var = fmaf(-mu, mu, s2 * (1.f / 256.f));
            float rsq = rsqrtf(var + EPS);
            float mr  = mu * rsq;
            acc.x = fmaf(e0, rsq, acc.x) - mr;
            acc.y = fmaf(e1, rsq, acc.y) - mr;
            acc.z = fmaf(e2, rsq, acc.z) - mr;
            acc.w = fmaf(e3, rsq, acc.w) - mr;
        }
    }
    __syncthreads();
    *(float4*)&Vs[w * 256 + l * 4] = acc;   // reuse Vs for cross-wave reduce
    __syncthreads();
    float r = Vs[tid] + Vs[256 + tid] + Vs[512 + tid] + Vs[768 + tid];
    part[(b * 16 + p) * 256 + tid] = r;
}

// K4: reduce 16 partials, apply lng_g / (4096 * lng_b), 256x128 GEMM + elu.
// OUTPUT IS FLOAT32 (reference output dtype).
__global__ __launch_bounds__(128) void k_out(
    const float* __restrict__ part,
    const float* __restrict__ lgg, const float* __restrict__ lgb,
    const float* __restrict__ Wf,  const float* __restrict__ bfb,
    float* __restrict__ out) {
    int b = blockIdx.x;
    int f = threadIdx.x;  // 128
    __shared__ float sh[256];
    for (int h = f; h < 256; h += 128) {
        float s = 0.f;
        #pragma unroll
        for (int p = 0; p < 16; ++p) s += part[(b * 16 + p) * 256 + h];
        sh[h] = fmaf(lgg[h], s, 4096.f * lgb[h]);
    }
    __syncthreads();
    float acc = bfb[f];
    for (int h = 0; h < 256; ++h)
        acc = fmaf(sh[h], Wf[h * 128 + f], acc);
    float r = acc > 0.f ? acc : __expf(acc) - 1.f;
    out[b * 128 + f] = r;
}

extern "C" void kernel_launch(void* const* d_in, const int* in_sizes, int n_in,
                              void* d_out, int out_size, void* d_ws, size_t ws_size,
                              hipStream_t stream) {
    const float* xa  = (const float*)d_in[0];
    const float* xb  = (const float*)d_in[1];
    const float* Wa  = (const float*)d_in[2];
    const float* ba  = (const float*)d_in[3];
    const float* Wb  = (const float*)d_in[4];
    const float* bb  = (const float*)d_in[5];
    const float* g0  = (const float*)d_in[6];
    const float* b0  = (const float*)d_in[7];
    const float* Wg  = (const float*)d_in[8];
    const float* bg  = (const float*)d_in[9];
    const float* lgg = (const float*)d_in[10];
    const float* lgb = (const float*)d_in[11];
    const float* Wf  = (const float*)d_in[12];
    const float* bfb = (const float*)d_in[13];
    float* out = (float*)d_out;

    float* ws   = (float*)d_ws;
    float* abar = ws + OFF_ABAR;
    float* U    = ws + OFF_U;
    float* V    = ws + OFF_V;
    float* part = ws + OFF_PART;

    k_embed_ln0<<<128, 256, 0, stream>>>(xa, xb, Wa, ba, Wb, bb, g0, b0, abar);
    k_uv<<<512, 256, 0, stream>>>(abar, Wg, bg, U, V);
    k_pair<<<2048, 256, 0, stream>>>(U, V, part);
    k_out<<<128, 128, 0, stream>>>(part, lgg, lgb, Wf, bfb, out);
}

// Round 4
// 179.229 us; speedup vs baseline: 1.0881x; 1.0881x over previous
//
#include <hip/hip_runtime.h>
#include <hip/hip_bf16.h>

#define EPS 1e-5f

// ---- workspace layout (float offsets) ----
#define OFF_ABAR 0          // 128*64*72   = 589824 floats
#define OFF_U    589824     // 128*64*256  = 2097152
#define OFF_V    2686976    // 2097152
#define OFF_PART 4784128    // 128*4*256   = 131072  -> total 4915200 fl = 19.7 MB

__device__ __forceinline__ float elu(float z) {
    return z > 0.f ? z : __expf(z) - 1.f;
}

// K1: fused split-embedding + LayerNorm over (N,E) per batch.
__global__ __launch_bounds__(256) void k_embed_ln0(
    const float* __restrict__ xa, const float* __restrict__ xb,
    const float* __restrict__ Wa, const float* __restrict__ ba,
    const float* __restrict__ Wb, const float* __restrict__ bb,
    const float* __restrict__ g0, const float* __restrict__ b0,
    float* __restrict__ abar) {
    int b = blockIdx.x;
    int tid = threadIdx.x;
    float vals[18];
    float s1 = 0.f, s2 = 0.f;
    for (int m = 0; m < 18; ++m) {
        int k = tid + 256 * m;
        int e = k % 72;
        int n = k / 72;
        float acc;
        if (n < 32) {
            acc = ba[e];
            const float* x = xa + (b * 32 + n) * 23;
            #pragma unroll
            for (int d = 0; d < 23; ++d) acc = fmaf(x[d], Wa[d * 72 + e], acc);
        } else {
            acc = bb[e];
            const float* x = xb + (b * 32 + (n - 32)) * 13;
            #pragma unroll
            for (int d = 0; d < 13; ++d) acc = fmaf(x[d], Wb[d * 72 + e], acc);
        }
        vals[m] = acc;
        s1 += acc;
        s2 = fmaf(acc, acc, s2);
    }
    #pragma unroll
    for (int off = 32; off >= 1; off >>= 1) {
        s1 += __shfl_xor(s1, off, 64);
        s2 += __shfl_xor(s2, off, 64);
    }
    __shared__ float r1[4], r2[4];
    int w = tid >> 6;
    if ((tid & 63) == 0) { r1[w] = s1; r2[w] = s2; }
    __syncthreads();
    float t1 = r1[0] + r1[1] + r1[2] + r1[3];
    float t2 = r2[0] + r2[1] + r2[2] + r2[3];
    float mean = t1 * (1.f / 4608.f);
    float var  = fmaf(-mean, mean, t2 * (1.f / 4608.f));
    float rsq  = rsqrtf(var + EPS);
    float* ab = abar + b * 4608;
    for (int m = 0; m < 18; ++m) {
        int k = tid + 256 * m;
        ab[k] = fmaf((vals[m] - mean) * rsq, g0[k], b0[k]);
    }
}

// K2: U = abar @ Wg[0:72,:] (+ b_g folded in), V = abar @ Wg[72:144,:].
__global__ __launch_bounds__(256) void k_uv(
    const float* __restrict__ abar, const float* __restrict__ Wg,
    const float* __restrict__ bg,
    float* __restrict__ U, float* __restrict__ V) {
    int blk = blockIdx.x;            // 512 blocks
    int b = blk >> 2;
    int q = blk & 3;                 // n-range [q*16, q*16+16)
    int h = threadIdx.x;
    __shared__ float sa[72 * 16];    // [e][n], 4.5 KB
    const float* src = abar + (b * 64 + q * 16) * 72;
    for (int k = threadIdx.x; k < 72 * 16; k += 256) {
        int e = k >> 4, n = k & 15;
        sa[k] = src[n * 72 + e];
    }
    __syncthreads();
    float u[16], v[16];
    #pragma unroll
    for (int n = 0; n < 16; ++n) { u[n] = 0.f; v[n] = 0.f; }
    for (int e = 0; e < 72; ++e) {
        float wu = Wg[e * 256 + h];
        float wv = Wg[(72 + e) * 256 + h];
        const float4* sp = (const float4*)&sa[e * 16];
        #pragma unroll
        for (int n4 = 0; n4 < 4; ++n4) {
            float4 s4 = sp[n4];
            u[n4*4+0] = fmaf(s4.x, wu, u[n4*4+0]); v[n4*4+0] = fmaf(s4.x, wv, v[n4*4+0]);
            u[n4*4+1] = fmaf(s4.y, wu, u[n4*4+1]); v[n4*4+1] = fmaf(s4.y, wv, v[n4*4+1]);
            u[n4*4+2] = fmaf(s4.z, wu, u[n4*4+2]); v[n4*4+2] = fmaf(s4.z, wv, v[n4*4+2]);
            u[n4*4+3] = fmaf(s4.w, wu, u[n4*4+3]); v[n4*4+3] = fmaf(s4.w, wv, v[n4*4+3]);
        }
    }
    float bgh = bg[h];
    int base = (b * 64 + q * 16) * 256 + h;
    #pragma unroll
    for (int n = 0; n < 16; ++n) {
        U[base + n * 256] = u[n] + bgh;   // b_g folded into U
        V[base + n * 256] = v[n];
    }
}

// K3: pairwise elu + LayerNorm(256) + sum over pairs — butterfly-free.
// grid = 128 b × 4 i-chunks of 16; block = 1024 threads (16 waves).
// LDS: V[b] 64 KB, XOR-swizzled: element (j,h) at j*256 + (h ^ ((j&7)<<2)).
//   Row-wise (fixed j, h chunks) AND column-ish (fixed h-chunk over j) b128
//   accesses are both conflict-minimal under this swizzle.
// Phase A: thread t owns pair (i = i0 + t/64, j = t%64): in-lane stats over h
//   (no cross-lane ops). Phase B: wave w owns i = i0+w, lane l owns h=4l..4l+3,
//   loops j; rsq/mr come from lane j of the same wave via 2 uniform shuffles.
__global__ __launch_bounds__(1024, 8) void k_pair(
    const float* __restrict__ U, const float* __restrict__ V,
    float* __restrict__ part) {
    int b  = blockIdx.x >> 2;
    int pc = blockIdx.x & 3;
    int i0 = pc * 16;
    int t = threadIdx.x;
    int w = t >> 6, l = t & 63;
    __shared__ float Vs[64 * 256];   // 64 KB
    const float* Vb = V + b * 16384;
    // stage V[b] swizzled (coalesced global float4; conflict-minimal LDS write)
    #pragma unroll
    for (int it = 0; it < 4; ++it) {
        int k = t * 4 + it * 4096;
        int j = k >> 8, h0 = k & 255;
        float4 val = *(const float4*)&Vb[k];
        *(float4*)&Vs[j * 256 + (h0 ^ ((j & 7) << 2))] = val;
    }
    __syncthreads();

    // ---- phase A: stats for pair (i = i0 + w, j = l) ----
    const float* Urow = U + (size_t)(b * 64 + i0 + w) * 256;
    int swzA = (l & 7) << 2;
    const float* VrowA = Vs + l * 256;
    float s1 = 0.f, s2 = 0.f;
    for (int c = 0; c < 64; ++c) {
        float4 u4 = *(const float4*)&Urow[c * 4];               // wave-uniform
        float4 v4 = *(const float4*)&VrowA[(c * 4) ^ swzA];
        float e0 = elu(u4.x + v4.x);
        float e1 = elu(u4.y + v4.y);
        float e2 = elu(u4.z + v4.z);
        float e3 = elu(u4.w + v4.w);
        s1 += (e0 + e1) + (e2 + e3);
        s2 = fmaf(e0, e0, fmaf(e1, e1, fmaf(e2, e2, fmaf(e3, e3, s2))));
    }
    float mu  = s1 * (1.f / 256.f);
    float var = fmaf(-mu, mu, s2 * (1.f / 256.f));
    float rsq = rsqrtf(var + EPS);
    float mr  = mu * rsq;

    // ---- phase B: accumulate over j for i = i0 + w, h = 4l..4l+3 ----
    float4 u4 = *(const float4*)&Urow[l * 4];                   // per-lane, coalesced
    float4 acc = make_float4(0.f, 0.f, 0.f, 0.f);
    for (int j = 0; j < 64; ++j) {
        float rj = __shfl(rsq, j, 64);
        float mj = __shfl(mr,  j, 64);
        float4 v4 = *(const float4*)&Vs[j * 256 + ((l * 4) ^ ((j & 7) << 2))];
        float e0 = elu(u4.x + v4.x);
        float e1 = elu(u4.y + v4.y);
        float e2 = elu(u4.z + v4.z);
        float e3 = elu(u4.w + v4.w);
        acc.x = fmaf(e0, rj, acc.x) - mj;
        acc.y = fmaf(e1, rj, acc.y) - mj;
        acc.z = fmaf(e2, rj, acc.z) - mj;
        acc.w = fmaf(e3, rj, acc.w) - mj;
    }

    // ---- block-level reduce over the 16 i's (reuse Vs) ----
    __syncthreads();
    *(float4*)&Vs[w * 256 + l * 4] = acc;
    __syncthreads();
    if (t < 256) {
        float r = 0.f;
        #pragma unroll
        for (int ww = 0; ww < 16; ++ww) r += Vs[ww * 256 + t];
        part[(b * 4 + pc) * 256 + t] = r;
    }
}

// K4: reduce 4 partials, apply lng_g / (4096 * lng_b), 256x128 GEMM + elu.
__global__ __launch_bounds__(128) void k_out(
    const float* __restrict__ part,
    const float* __restrict__ lgg, const float* __restrict__ lgb,
    const float* __restrict__ Wf,  const float* __restrict__ bfb,
    float* __restrict__ out) {
    int b = blockIdx.x;
    int f = threadIdx.x;  // 128
    __shared__ float sh[256];
    for (int h = f; h < 256; h += 128) {
        float s = part[(b * 4 + 0) * 256 + h] + part[(b * 4 + 1) * 256 + h]
                + part[(b * 4 + 2) * 256 + h] + part[(b * 4 + 3) * 256 + h];
        sh[h] = fmaf(lgg[h], s, 4096.f * lgb[h]);
    }
    __syncthreads();
    float acc = bfb[f];
    for (int h = 0; h < 256; ++h)
        acc = fmaf(sh[h], Wf[h * 128 + f], acc);
    float r = acc > 0.f ? acc : __expf(acc) - 1.f;
    out[b * 128 + f] = r;
}

extern "C" void kernel_launch(void* const* d_in, const int* in_sizes, int n_in,
                              void* d_out, int out_size, void* d_ws, size_t ws_size,
                              hipStream_t stream) {
    const float* xa  = (const float*)d_in[0];
    const float* xb  = (const float*)d_in[1];
    const float* Wa  = (const float*)d_in[2];
    const float* ba  = (const float*)d_in[3];
    const float* Wb  = (const float*)d_in[4];
    const float* bb  = (const float*)d_in[5];
    const float* g0  = (const float*)d_in[6];
    const float* b0  = (const float*)d_in[7];
    const float* Wg  = (const float*)d_in[8];
    const float* bg  = (const float*)d_in[9];
    const float* lgg = (const float*)d_in[10];
    const float* lgb = (const float*)d_in[11];
    const float* Wf  = (const float*)d_in[12];
    const float* bfb = (const float*)d_in[13];
    float* out = (float*)d_out;

    float* ws   = (float*)d_ws;
    float* abar = ws + OFF_ABAR;
    float* U    = ws + OFF_U;
    float* V    = ws + OFF_V;
    float* part = ws + OFF_PART;

    k_embed_ln0<<<128, 256, 0, stream>>>(xa, xb, Wa, ba, Wb, bb, g0, b0, abar);
    k_uv<<<512, 256, 0, stream>>>(abar, Wg, bg, U, V);
    k_pair<<<512, 1024, 0, stream>>>(U, V, part);
    k_out<<<128, 128, 0, stream>>>(part, lgg, lgb, Wf, bfb, out);
}